// Round 14
// baseline (366.495 us; speedup 1.0000x reference)
//
#include <hip/hip_runtime.h>

// GraphSAGE 2-layer, mean agg. N=50000, E=800000, F: 128 -> 256 -> 128.
// CSR build (XCD-range-partitioned counting sort) -> gather1 -> MFMA L1 ->
// MFMA L2 -> gather2(accum). Layer-2 scatter replaced by gather (linearity).
// GEMM: B-half resident in LDS once per block; A streamed global->reg;
// no inner barriers.
// NOTE: harness delivers integer inputs as int32 (NOT int64 as in the JAX ref).
constexpr int NN = 50000;
constexpr int EE = 800000;
constexpr int FI = 128;
constexpr int FO = 128;

typedef __attribute__((ext_vector_type(4))) float f32x4;
typedef __attribute__((ext_vector_type(8))) short bf16x8;

__device__ inline unsigned short f2bf(float f) {   // RNE f32 -> bf16
    union { float f; unsigned u; } v; v.f = f;
    unsigned r = v.u + 0x7FFFu + ((v.u >> 16) & 1u);
    return (unsigned short)(r >> 16);
}
__device__ inline float bf2f(unsigned short u) {
    union { unsigned u; float f; } v; v.u = ((unsigned)u) << 16; return v.f;
}

// ============================ CSR build ============================
// cnt padded: one counter per 64B line (cnt[n*16]).

__global__ void deg_i_kernel(const int* __restrict__ ei, int* __restrict__ cnt) {
    int e = blockIdx.x * blockDim.x + threadIdx.x;
    if (e < EE) atomicAdd(&cnt[ei[EE + e] << 4], 1);
}

// 3-phase exclusive scan of cnt -> rowptr[0..NN]; phase1 also emits rdeg.
constexpr int SCAN_NBLK = (NN + 1023) / 1024;   // 49

__global__ __launch_bounds__(1024) void scan_phase1(const int* __restrict__ cnt,
                                                    int* __restrict__ rowptr,
                                                    int* __restrict__ bsum,
                                                    float* __restrict__ rdeg) {
    __shared__ int wsum[16];
    const int tid = threadIdx.x;
    const int lane = tid & 63;
    const int wid = tid >> 6;
    int i = blockIdx.x * 1024 + tid;
    int v = (i < NN) ? cnt[i << 4] : 0;
    if (i < NN) rdeg[i] = 1.0f / fmaxf((float)v, 1.0f);
    int s = v;
#pragma unroll
    for (int off = 1; off < 64; off <<= 1) {
        int t = __shfl_up(s, off, 64);
        if (lane >= off) s += t;
    }
    if (lane == 63) wsum[wid] = s;
    __syncthreads();
    if (wid == 0) {
        int ws = (lane < 16) ? wsum[lane] : 0;
#pragma unroll
        for (int off = 1; off < 16; off <<= 1) {
            int t = __shfl_up(ws, off, 64);
            if (lane >= off) ws += t;
        }
        if (lane < 16) wsum[lane] = ws;
    }
    __syncthreads();
    int woff = (wid > 0) ? wsum[wid - 1] : 0;
    if (i < NN) rowptr[i] = woff + s - v;           // exclusive within block
    if (tid == 0) bsum[blockIdx.x] = wsum[15];      // block total
}

__global__ void scan_phase2(int* __restrict__ bsum) {   // one wave, NBLK<=64
    int lane = threadIdx.x;
    int v = (lane < SCAN_NBLK) ? bsum[lane] : 0;
    int s = v;
#pragma unroll
    for (int off = 1; off < 64; off <<= 1) {
        int t = __shfl_up(s, off, 64);
        if (lane >= off) s += t;
    }
    if (lane < SCAN_NBLK) bsum[lane] = s - v;       // exclusive block offsets
}

__global__ void scan_phase3(int* __restrict__ rowptr, const int* __restrict__ bsum) {
    int i = blockIdx.x * blockDim.x + threadIdx.x;
    if (i < NN) rowptr[i] += bsum[i >> 10];
    else if (i == NN) rowptr[NN] = EE;              // sentinel end
}

// XCD-range-partitioned count-down slot assign: block b owns dst range
// (b&7)*6250..+6250 over edge window (b>>3). Round-robin dispatch puts all
// writers of a csr_src region on one XCD -> no L2 line ping-pong.
// Correctness does not depend on the mapping (perf heuristic only).
constexpr int EDGE_CHUNK = 16384;
constexpr int NCHUNKE = (EE + EDGE_CHUNK - 1) / EDGE_CHUNK;   // 49
constexpr int DRANGE = NN / 8;                                 // 6250

__global__ void slot_kernel(const int* __restrict__ ei,
                            const int* __restrict__ rowptr,
                            int* __restrict__ cnt,
                            int* __restrict__ csr_src) {
    int rng = blockIdx.x & 7;
    int chunk = blockIdx.x >> 3;
    int lo = rng * DRANGE;
    int hi = lo + DRANGE;
    int e0 = chunk * EDGE_CHUNK;
    int e1 = min(e0 + EDGE_CHUNK, EE);
    for (int e = e0 + threadIdx.x; e < e1; e += 256) {
        int dst = ei[EE + e];
        if (dst >= lo && dst < hi) {
            int old = atomicSub(&cnt[dst << 4], 1);
            csr_src[rowptr[dst] + old - 1] = ei[e];
        }
    }
}

// ============================ gathers ============================
// One 64-lane wave per node, bf16 rows, masked 8-deep load batches.

// mean over neighbors of bf16 x (A1 cols [128,256)) -> bf16 A1 cols [0,128).
__global__ __launch_bounds__(256) void gather_mean_bf16(
    const int* __restrict__ rowptr, const int* __restrict__ csr_src,
    const float* __restrict__ rdeg,
    unsigned short* __restrict__ A1)        // [N][256] bf16
{
    int node = blockIdx.x * 4 + (threadIdx.x >> 6);
    if (node >= NN) return;
    int lane = threadIdx.x & 63;
    int f = lane * 2;
    int start = rowptr[node];
    int end = rowptr[node + 1];
    float ax[8], ay[8];
#pragma unroll
    for (int u = 0; u < 8; ++u) { ax[u] = 0.f; ay[u] = 0.f; }
    for (int j = start; j < end; j += 8) {
        int si[8];
        float w[8];
#pragma unroll
        for (int u = 0; u < 8; ++u) {
            int idx = j + u;
            si[u] = csr_src[idx < end ? idx : start];   // safe dup (line-hot)
            w[u] = (idx < end) ? 1.f : 0.f;
        }
        ushort2 v[8];
#pragma unroll
        for (int u = 0; u < 8; ++u)
            v[u] = *reinterpret_cast<const ushort2*>(A1 + (size_t)si[u] * 256 + 128 + f);
#pragma unroll
        for (int u = 0; u < 8; ++u) {
            ax[u] = fmaf(w[u], bf2f(v[u].x), ax[u]);
            ay[u] = fmaf(w[u], bf2f(v[u].y), ay[u]);
        }
    }
    float s = rdeg[node];
    float sx = ((ax[0] + ax[1]) + (ax[2] + ax[3])) + ((ax[4] + ax[5]) + (ax[6] + ax[7]));
    float sy = ((ay[0] + ay[1]) + (ay[2] + ay[3])) + ((ay[4] + ay[5]) + (ay[6] + ay[7]));
    ushort2 o;
    o.x = f2bf(sx * s);
    o.y = f2bf(sy * s);
    *reinterpret_cast<ushort2*>(A1 + (size_t)node * 256 + f) = o;
}

// out[node] += rdeg[node] * sum g2b[src]   (g2b bf16 [N][128], out f32)
__global__ __launch_bounds__(256) void gather_accum_f32(
    const int* __restrict__ rowptr, const int* __restrict__ csr_src,
    const float* __restrict__ rdeg, const unsigned short* __restrict__ g2b,
    float* __restrict__ outp)
{
    int node = blockIdx.x * 4 + (threadIdx.x >> 6);
    if (node >= NN) return;
    int lane = threadIdx.x & 63;
    int f = lane * 2;
    int start = rowptr[node];
    int end = rowptr[node + 1];
    float ax[8], ay[8];
#pragma unroll
    for (int u = 0; u < 8; ++u) { ax[u] = 0.f; ay[u] = 0.f; }
    for (int j = start; j < end; j += 8) {
        int si[8];
        float w[8];
#pragma unroll
        for (int u = 0; u < 8; ++u) {
            int idx = j + u;
            si[u] = csr_src[idx < end ? idx : start];
            w[u] = (idx < end) ? 1.f : 0.f;
        }
        ushort2 v[8];
#pragma unroll
        for (int u = 0; u < 8; ++u)
            v[u] = *reinterpret_cast<const ushort2*>(g2b + (size_t)si[u] * 128 + f);
#pragma unroll
        for (int u = 0; u < 8; ++u) {
            ax[u] = fmaf(w[u], bf2f(v[u].x), ax[u]);
            ay[u] = fmaf(w[u], bf2f(v[u].y), ay[u]);
        }
    }
    float s = rdeg[node];
    float sx = ((ax[0] + ax[1]) + (ax[2] + ax[3])) + ((ax[4] + ax[5]) + (ax[6] + ax[7]));
    float sy = ((ay[0] + ay[1]) + (ay[2] + ay[3])) + ((ay[4] + ay[5]) + (ay[6] + ay[7]));
    float* p = outp + (size_t)node * FO + f;
    float2 o = *reinterpret_cast<float2*>(p);
    o.x += sx * s;
    o.y += sy * s;
    *reinterpret_cast<float2*>(p) = o;
}

// ============================ prep kernels ============================

__global__ void cast_x_kernel(const float* __restrict__ x,
                              unsigned short* __restrict__ A1) {
    int i = blockIdx.x * blockDim.x + threadIdx.x;    // N*32 float4s
    if (i >= NN * 32) return;
    int n = i >> 5;
    int c4 = (i & 31) * 4;
    float4 v = *reinterpret_cast<const float4*>(x + (size_t)n * FI + c4);
    ushort4 o;
    o.x = f2bf(v.x); o.y = f2bf(v.y); o.z = f2bf(v.z); o.w = f2bf(v.w);
    *reinterpret_cast<ushort4*>(A1 + (size_t)n * 256 + 128 + c4) = o;
}

// B1T[n][k] = k<128 ? W1l[k][n] : W1r[k-128][n]     (W1* are [128][256])
// B2T[n][k] = n<128 ? W2r[k][n] : W2l[k][n-128]     (W2* are [256][128])
__global__ void prep_weights(const float* __restrict__ W1l, const float* __restrict__ W1r,
                             const float* __restrict__ W2l, const float* __restrict__ W2r,
                             unsigned short* __restrict__ B1T,
                             unsigned short* __restrict__ B2T) {
    int i = blockIdx.x * blockDim.x + threadIdx.x;
    if (i >= 256 * 256) return;
    int n = i >> 8, k = i & 255;
    float v1 = (k < 128) ? W1l[(size_t)k * 256 + n] : W1r[(size_t)(k - 128) * 256 + n];
    B1T[(size_t)n * 256 + k] = f2bf(v1);
    float v2 = (n < 128) ? W2r[(size_t)k * 128 + n] : W2l[(size_t)k * 128 + (n - 128)];
    B2T[(size_t)n * 256 + k] = f2bf(v2);
}

// ============================ MFMA GEMM ============================
// C[N x 256] = A[N x 256] @ BT[256 x 256]^T, bf16 in, f32 acc.
// Grid 512: half = blockIdx&1 (output cols half*128..+128), bslot = blockIdx>>1.
// Block stages its B-half ONCE into LDS ([128][BPAD] bf16, 66 KB -> 2 blk/CU),
// then loops 128-row chunks (stride 256) with NO barriers: each wave owns 32
// rows, streams A fragments global->reg (16x dwordx4, independent), 128 MFMA.
// BPAD=264: dword-bank = 132*r mod 32 = 4r mod 32 -> 2-way max (free, m136).
// R13 FIX: stage loop was half-sized (128*16 segs = cols 0..127 only) ->
// Bl[r][128..255] uninitialized -> NaN. Full row = 32 x 16B segs = 128*32.
// MODE 0 (L1): +bias[col], relu, bf16 h.  MODE 1 (L2): half0 -> out=+bias f32;
// half1 -> g2b bf16.
constexpr int BPAD = 264;
constexpr int NCHUNK = (NN + 127) / 128;   // 391
constexpr int GEMM_BLK = 512;

template<int MODE>
__global__ __launch_bounds__(256) void mfma_gemm(
    const unsigned short* __restrict__ A,    // [N][256] bf16
    const unsigned short* __restrict__ BT,   // [256][256] bf16
    const float* __restrict__ bias,
    unsigned short* __restrict__ out_bf,     // MODE 0: h
    float* __restrict__ out_f0,              // MODE 1: out
    unsigned short* __restrict__ g2b)        // MODE 1: g2 bf16
{
    __shared__ unsigned short Bl[128][BPAD];   // 66 KB

    const int t = threadIdx.x;
    const int wid = t >> 6;
    const int lane = t & 63;
    const int l15 = lane & 15;
    const int lhi = lane >> 4;
    const int half = blockIdx.x & 1;
    const int bslot = blockIdx.x >> 1;

    // stage B half once: 128 rows x 256 shorts = 32 x 16B segments per row
    for (int i = t; i < 128 * 32; i += 256) {
        int r = i >> 5;
        int c = (i & 31) * 8;
        *reinterpret_cast<uint4*>(&Bl[r][c]) =
            *reinterpret_cast<const uint4*>(BT + ((size_t)(half * 128 + r)) * 256 + c);
    }
    __syncthreads();

    for (int chunk = bslot; chunk < NCHUNK; chunk += GEMM_BLK / 2) {
        const int rb = chunk * 128 + wid * 32;

        bf16x8 a[2][8];
#pragma unroll
        for (int m = 0; m < 2; ++m) {
            int row = rb + m * 16 + l15;
            if (row >= NN) row = NN - 1;             // clamp; write guarded
            const unsigned short* ap = A + (size_t)row * 256 + lhi * 8;
#pragma unroll
            for (int ks = 0; ks < 8; ++ks)
                a[m][ks] = *reinterpret_cast<const bf16x8*>(ap + ks * 32);
        }

        f32x4 acc[2][8];
#pragma unroll
        for (int m = 0; m < 2; ++m)
#pragma unroll
            for (int n = 0; n < 8; ++n) acc[m][n] = f32x4{0.f, 0.f, 0.f, 0.f};

#pragma unroll
        for (int ks = 0; ks < 8; ++ks) {
#pragma unroll
            for (int n = 0; n < 8; ++n) {
                bf16x8 b = *reinterpret_cast<const bf16x8*>(
                    &Bl[n * 16 + l15][ks * 32 + lhi * 8]);
                acc[0][n] = __builtin_amdgcn_mfma_f32_16x16x32_bf16(a[0][ks], b, acc[0][n], 0, 0, 0);
                acc[1][n] = __builtin_amdgcn_mfma_f32_16x16x32_bf16(a[1][ks], b, acc[1][n], 0, 0, 0);
            }
        }

#pragma unroll
        for (int n = 0; n < 8; ++n) {
            int colh = n * 16 + l15;                // 0..127 within half
            int col = half * 128 + colh;
#pragma unroll
            for (int m = 0; m < 2; ++m) {
#pragma unroll
                for (int j = 0; j < 4; ++j) {
                    int row = rb + m * 16 + lhi * 4 + j;
                    if (row < NN) {
                        float v = acc[m][n][j];
                        if (MODE == 0) {
                            v += bias[col];
                            v = fmaxf(v, 0.f);
                            out_bf[(size_t)row * 256 + col] = f2bf(v);
                        } else {
                            if (half == 0) out_f0[(size_t)row * 128 + colh] = v + bias[colh];
                            else           g2b[(size_t)row * 128 + colh] = f2bf(v);
                        }
                    }
                }
            }
        }
    }
}

// ============================ launch ============================

extern "C" void kernel_launch(void* const* d_in, const int* in_sizes, int n_in,
                              void* d_out, int out_size, void* d_ws, size_t ws_size,
                              hipStream_t stream) {
    const float* x   = (const float*)d_in[0];
    const int*   ei  = (const int*)d_in[1];   // harness stages integers as int32
    const float* W1l = (const float*)d_in[2];
    const float* W1r = (const float*)d_in[3];
    const float* b1  = (const float*)d_in[4];
    const float* W2l = (const float*)d_in[5];
    const float* W2r = (const float*)d_in[6];
    const float* b2  = (const float*)d_in[7];
    float*       out = (float*)d_out;

    // ws layout (4B units): cnt[N*16 padded] | rowptr[N+16] | csr_src[E] | rdeg[N]
    //   | A1 (N*256 bf16; g2b reuses after L1) | h (N*256 bf16) | B1T | B2T | bsum
    const size_t needed =
        ((size_t)NN * 16 + (NN + 16) + EE + NN
         + (size_t)NN * 128 * 2 + 65536 + 64) * 4;   // ~58.3 MB (< proven 80.6)
    if (ws_size < needed) return;

    int*            cnt     = (int*)d_ws;                       // padded counters
    int*            rowptr  = cnt + (size_t)NN * 16;            // [N+1] exclusive
    int*            csr_src = rowptr + (NN + 16);
    float*          rdeg    = (float*)(csr_src + EE);
    unsigned short* A1      = (unsigned short*)(rdeg + NN);     // [N][256] bf16
    unsigned short* g2b     = A1;                               // [N][128] bf16 (after L1)
    unsigned short* h       = A1 + (size_t)NN * 256;            // [N][256] bf16
    unsigned short* B1T     = h + (size_t)NN * 256;
    unsigned short* B2T     = B1T + 256 * 256;
    int*            bsum    = (int*)(B2T + 256 * 256);

    hipMemsetAsync(cnt, 0, (size_t)NN * 16 * sizeof(int), stream);
    prep_weights<<<256, 256, 0, stream>>>(W1l, W1r, W2l, W2r, B1T, B2T);
    cast_x_kernel<<<(NN * 32 + 255) / 256, 256, 0, stream>>>(x, A1);
    deg_i_kernel<<<(EE + 255) / 256, 256, 0, stream>>>(ei, cnt);
    scan_phase1<<<SCAN_NBLK, 1024, 0, stream>>>(cnt, rowptr, bsum, rdeg);
    scan_phase2<<<1, 64, 0, stream>>>(bsum);
    scan_phase3<<<(NN + 256) / 256, 256, 0, stream>>>(rowptr, bsum);
    slot_kernel<<<NCHUNKE * 8, 256, 0, stream>>>(ei, rowptr, cnt, csr_src);

    // layer 1: A1[:,0:128] = mean(bf16 x); h = relu(A1 @ B1T^T + b1) (bf16)
    gather_mean_bf16<<<(NN + 3) / 4, 256, 0, stream>>>(rowptr, csr_src, rdeg, A1);
    mfma_gemm<0><<<GEMM_BLK, 256, 0, stream>>>(A1, B1T, b1, h, nullptr, nullptr);

    // layer 2: out = h@W2r + b2 (f32); g2b = bf16(h@W2l) overlaying dead A1
    mfma_gemm<1><<<GEMM_BLK, 256, 0, stream>>>(h, B2T, b2, nullptr, out, g2b);

    // out[n] += rdeg[n] * sum g2b[src]
    gather_accum_f32<<<(NN + 3) / 4, 256, 0, stream>>>(rowptr, csr_src, rdeg, g2b, out);
}